// Round 8
// baseline (1846.028 us; speedup 1.0000x reference)
//
#include <hip/hip_runtime.h>
#include <hip/hip_fp16.h>

#define TT 30
#define BATCH 8192

typedef _Float16 f16x8v __attribute__((ext_vector_type(8)));
typedef float    f32x4v __attribute__((ext_vector_type(4)));
typedef unsigned int u32x4v __attribute__((ext_vector_type(4)));

__device__ __forceinline__ float sigf(float x) { return 1.0f / (1.0f + __expf(-x)); }

__device__ __forceinline__ f16x8v ldb16(const __half* p) {
    return __builtin_bit_cast(f16x8v, *(const u32x4v*)p);
}
__device__ __forceinline__ f32x4v mfma16(f16x8v a, f16x8v b, f32x4v c) {
    return __builtin_amdgcn_mfma_f32_16x16x32_f16(a, b, c, 0, 0, 0);
}

// ---------------------------------------------------------------------------
// x (B,T,126) fp32 -> x16 (B,T,128) f16, zero-padded cols 126..127
// ---------------------------------------------------------------------------
__global__ __launch_bounds__(256)
void x_to_f16(const float* __restrict__ x, __half* __restrict__ x16)
{
    const size_t i = (size_t)blockIdx.x * 256 + threadIdx.x;  // < B*T*128
    const int k = (int)(i & 127);
    const size_t bt = i >> 7;
    x16[i] = (k < 126) ? __float2half(x[bt * 126 + k]) : __half(0.0f);
}

// ---------------------------------------------------------------------------
// Pack LSTM weights into MFMA B-fragment order, W waves per direction.
// Dest flat: [dir][wave W][nt NT][kt KT][lane 64][jj 8], fragment element
// B[k = kt*32 + (lane>>4)*8 + jj][col = g*U + w*(U/W) + jhi*16 + (lane&15)]
// with g = nt/JH, jhi = nt%JH, JH = U/(16W), NT = 4*JH.
// K rows: [W rows 0..DINP) (>=DINS zero-padded), then Urec rows.
// (Layout depends only on W, not on the M-tiling of the LSTM kernel.)
// ---------------------------------------------------------------------------
template<int DINS, int DINP, int U, int W>
__global__ __launch_bounds__(256)
void pack_b(const float* __restrict__ wf, const float* __restrict__ uf,
            const float* __restrict__ wb, const float* __restrict__ ub,
            __half* __restrict__ dst)
{
    constexpr int JH = U / (16 * W), NT = 4 * JH, KT = (DINP + U) / 32;
    const int i = blockIdx.x * 256 + threadIdx.x;   // < 2*W*NT*KT*512
    const int jj   = i & 7;
    const int lane = (i >> 3) & 63;
    int rest = i >> 9;
    const int kt = rest % KT; rest /= KT;
    const int nt = rest % NT; rest /= NT;
    const int w  = rest % W;
    const int d  = rest / W;
    const int g = nt / JH, jhi = nt % JH;
    const int col = g * U + w * (U / W) + jhi * 16 + (lane & 15);
    const int k = kt * 32 + (lane >> 4) * 8 + jj;
    const float* __restrict__ Wm = d ? wb : wf;
    const float* __restrict__ Ur = d ? ub : uf;
    float v;
    if (k < DINS)      v = Wm[(size_t)k * (4 * U) + col];
    else if (k < DINP) v = 0.0f;
    else               v = Ur[(size_t)(k - DINP) * (4 * U) + col];
    dst[i] = __float2half(v);
}

// ---------------------------------------------------------------------------
// Pack d1w (15360,256) into per-(t,dir) B-fragment slabs, W waves:
// [t 30][d 2][w W][nt NT1][kt 8][lane 64][jj 8], NT1 = 256/(16W);
// element = d1w[(t*512 + d*256 + k)*256 + n], k = kt*32+(lane>>4)*8+jj,
// n = w*(256/W) + nt*16 + (lane&15).
// ---------------------------------------------------------------------------
template<int W>
__global__ __launch_bounds__(256)
void pack_d1(const float* __restrict__ src, __half* __restrict__ dst)
{
    constexpr int NT1 = 256 / (16 * W);
    const int i = blockIdx.x * 256 + threadIdx.x;   // < 3,932,160
    const int jj   = i & 7;
    const int lane = (i >> 3) & 63;
    const int kt   = (i >> 9) & 7;
    int rest = i >> 12;
    const int nt = rest % NT1; rest /= NT1;
    const int w  = rest % W;   rest /= W;
    const int d  = rest & 1;
    const int t  = rest >> 1;
    const int n = w * (256 / W) + nt * 16 + (lane & 15);
    const int k = kt * 32 + (lane >> 4) * 8 + jj;
    dst[i] = __float2half(src[(size_t)(t * 512 + d * 256 + k) * 256 + n]);
}

// ---------------------------------------------------------------------------
// MFMA bidirectional LSTM layer body. Block = (MT*16) batch rows x one
// direction, W waves (64*W threads), iterates all TT steps.
// Per step: Z[M][4U] = [x_t | h] @ [W;U] + b via 16x16x32 f16 MFMA.
// Wave w owns N-columns {g*U + w*(U/W) + jhi*16 + c}.
// h (f16) double-buffered in LDS (row stride U+8) -> ONE barrier per step.
// c (fp32) in VGPRs at C-layout (row=quad*4+reg, col=lane&15).
// FUSE (lstm3): per-step rank-256 dense1 MFMA update; accumulator in LDS
// (a1s[MT*4][NTH], per-thread-private column, conflict-free), register-
// resident only during the dense1 phase (R7: killed the R2-R6 scratch
// spill, WRITE_SIZE 398->25 MB). FUSE Z-loops use unroll 1: at 8 waves/
// SIMD the register budget is 64/wave (incl AGPR) and TLP covers ILP.
// R7 diagnosis: at 1 block/CU (16 waves lockstep, 4 waves/SIMD) 52% of
// cycles were pipe-idle stall -> lstm3 now runs MT=2, 512 blocks,
// 2 blocks/CU, 8 waves/SIMD to double latency hiding and decorrelate
// barrier stalls. Weight packs depend only on W (unchanged).
// ---------------------------------------------------------------------------
template<int DIN, int U, bool FUSE, int W, int MT>
__device__ __forceinline__
void lstm_body(const __half* __restrict__ xin,    // (B,T,DIN) f16
               const __half* __restrict__ PB,     // packed weights
               const float* __restrict__ biasf, const float* __restrict__ biasb,
               __half* __restrict__ out,          // (B,T,2U) f16 (non-FUSE)
               const __half* __restrict__ PD1, float* __restrict__ d1o)
{
    constexpr int NTH = 64 * W;
    constexpr int M = 16 * MT;
    constexpr int JH = U / (16 * W);          // per-gate 16-col tiles per wave
    constexpr int NT = 4 * JH;
    constexpr int KT = (DIN + U) / 32, KTI = DIN / 32;
    constexpr int HS = U + 8;
    constexpr int NT1 = FUSE ? (256 / (16 * W)) : 1;
    static_assert(!FUSE || NT1 == 1, "FUSE path assumes one 16-col dense1 tile per wave");
    const int dir = blockIdx.y;
    const int tid = threadIdx.x;
    const int lane = tid & 63, wv = tid >> 6;
    const int l16 = lane & 15, quad = lane >> 4;
    const int row0 = blockIdx.x * M;
    const float* __restrict__ bias = dir ? biasb : biasf;

    __shared__ __align__(16) __half hb[2][M][HS];
    // dense1 accumulator: per-thread-private column -> no conflicts, no races
    __shared__ float a1s[FUSE ? MT * 4 : 1][FUSE ? NTH : 1];

    float bg[NT];
#pragma unroll
    for (int nt = 0; nt < NT; ++nt) {
        const int g = nt / JH, jhi = nt % JH;
        bg[nt] = bias[g * U + wv * (U / W) + jhi * 16 + l16];
    }

    float creg[MT][JH][4];
#pragma unroll
    for (int mt = 0; mt < MT; ++mt)
#pragma unroll
        for (int jhi = 0; jhi < JH; ++jhi)
#pragma unroll
            for (int r = 0; r < 4; ++r) creg[mt][jhi][r] = 0.0f;

    if constexpr (FUSE) {
#pragma unroll
        for (int j = 0; j < MT * 4; ++j) a1s[j][tid] = 0.0f;
    }

    for (int i = tid; i < M * HS; i += NTH) ((__half*)hb[0])[i] = __half(0.0f);
    __syncthreads();

    const __half* __restrict__ PBw = PB + (size_t)(dir * W + wv) * (NT * KT * 512);
    const __half* __restrict__ xbase =
        xin + (size_t)(row0 + l16) * TT * DIN + quad * 8;

    int pb = 0;
#pragma unroll 1
    for (int s = 0; s < TT; ++s) {
        const int t = dir ? (TT - 1 - s) : s;
        const __half* __restrict__ xt = xbase + (size_t)t * DIN;

        f32x4v acc[MT][NT];
#pragma unroll
        for (int mt = 0; mt < MT; ++mt)
#pragma unroll
            for (int nt = 0; nt < NT; ++nt)
                acc[mt][nt] = f32x4v{bg[nt], bg[nt], bg[nt], bg[nt]};

        if constexpr (FUSE) {
            // unroll 1: tight 64-reg budget at 8 waves/SIMD
#pragma unroll 1
            for (int kt = 0; kt < KTI; ++kt) {
                f16x8v a[MT];
#pragma unroll
                for (int mt = 0; mt < MT; ++mt)
                    a[mt] = ldb16(xt + (size_t)mt * 16 * TT * DIN + kt * 32);
                const __half* bp = PBw + (size_t)kt * 512 + lane * 8;
#pragma unroll
                for (int nt = 0; nt < NT; ++nt) {
                    const f16x8v b = ldb16(bp + (size_t)nt * KT * 512);
#pragma unroll
                    for (int mt = 0; mt < MT; ++mt)
                        acc[mt][nt] = mfma16(a[mt], b, acc[mt][nt]);
                }
            }
#pragma unroll 1
            for (int kt = KTI; kt < KT; ++kt) {
                f16x8v a[MT];
#pragma unroll
                for (int mt = 0; mt < MT; ++mt)
                    a[mt] = ldb16(&hb[pb][mt * 16 + l16][(kt - KTI) * 32 + quad * 8]);
                const __half* bp = PBw + (size_t)kt * 512 + lane * 8;
#pragma unroll
                for (int nt = 0; nt < NT; ++nt) {
                    const f16x8v b = ldb16(bp + (size_t)nt * KT * 512);
#pragma unroll
                    for (int mt = 0; mt < MT; ++mt)
                        acc[mt][nt] = mfma16(a[mt], b, acc[mt][nt]);
                }
            }
        } else {
#pragma unroll 2
            for (int kt = 0; kt < KTI; ++kt) {
                f16x8v a[MT];
#pragma unroll
                for (int mt = 0; mt < MT; ++mt)
                    a[mt] = ldb16(xt + (size_t)mt * 16 * TT * DIN + kt * 32);
                const __half* bp = PBw + (size_t)kt * 512 + lane * 8;
#pragma unroll
                for (int nt = 0; nt < NT; ++nt) {
                    const f16x8v b = ldb16(bp + (size_t)nt * KT * 512);
#pragma unroll
                    for (int mt = 0; mt < MT; ++mt)
                        acc[mt][nt] = mfma16(a[mt], b, acc[mt][nt]);
                }
            }
#pragma unroll 2
            for (int kt = KTI; kt < KT; ++kt) {
                f16x8v a[MT];
#pragma unroll
                for (int mt = 0; mt < MT; ++mt)
                    a[mt] = ldb16(&hb[pb][mt * 16 + l16][(kt - KTI) * 32 + quad * 8]);
                const __half* bp = PBw + (size_t)kt * 512 + lane * 8;
#pragma unroll
                for (int nt = 0; nt < NT; ++nt) {
                    const f16x8v b = ldb16(bp + (size_t)nt * KT * 512);
#pragma unroll
                    for (int mt = 0; mt < MT; ++mt)
                        acc[mt][nt] = mfma16(a[mt], b, acc[mt][nt]);
                }
            }
        }

        // ---- gates / state (C-layout: row=quad*4+r, col=l16) ----
        // h streamed straight to LDS (no staging array).
#pragma unroll
        for (int mt = 0; mt < MT; ++mt)
#pragma unroll
            for (int jhi = 0; jhi < JH; ++jhi)
#pragma unroll
                for (int r = 0; r < 4; ++r) {
                    const float zi = acc[mt][0 * JH + jhi][r];
                    const float zf = acc[mt][1 * JH + jhi][r];
                    const float zg = acc[mt][2 * JH + jhi][r];
                    const float zo = acc[mt][3 * JH + jhi][r];
                    const float cn = sigf(zf) * creg[mt][jhi][r] + sigf(zi) * fmaxf(zg, 0.0f);
                    creg[mt][jhi][r] = cn;
                    hb[1 - pb][mt * 16 + quad * 4 + r][wv * (U / W) + jhi * 16 + l16] =
                        __float2half(sigf(zo) * fmaxf(cn, 0.0f));
                }
        __syncthreads();   // h(s) visible; also fences hb[pb] overwrite next step

        if constexpr (FUSE) {
            // dense1 rank-256 update: a1s += h_t @ d1w_slab(t,dir).
            // acc regs live only within this phase (load LDS -> mfma -> store).
            const __half* slab = PD1 + (size_t)((t * 2 + dir) * W + wv) * (NT1 * 8 * 512)
                               + lane * 8;
            f32x4v c1[MT];
#pragma unroll
            for (int mt = 0; mt < MT; ++mt)
#pragma unroll
                for (int r = 0; r < 4; ++r) c1[mt][r] = a1s[mt * 4 + r][tid];
#pragma unroll 2
            for (int kt = 0; kt < 8; ++kt) {
                const f16x8v b = ldb16(slab + (size_t)kt * 512);
#pragma unroll
                for (int mt = 0; mt < MT; ++mt) {
                    const f16x8v a = ldb16(&hb[1 - pb][mt * 16 + l16][kt * 32 + quad * 8]);
                    c1[mt] = mfma16(a, b, c1[mt]);
                }
            }
#pragma unroll
            for (int mt = 0; mt < MT; ++mt)
#pragma unroll
                for (int r = 0; r < 4; ++r) a1s[mt * 4 + r][tid] = c1[mt][r];
        } else {
            // coalesced h-out: (B,T,2U), this block's M rows, dir half
            constexpr int CH = U / 8;   // 16B chunks per row
            for (int i = tid; i < M * CH; i += NTH) {
                const int r = i / CH, cc = (i % CH) * 8;
                *(u32x4v*)(out + ((size_t)(row0 + r) * TT + t) * (2 * U) + dir * U + cc) =
                    *(const u32x4v*)&hb[1 - pb][r][cc];
            }
        }
        pb ^= 1;
    }

    if constexpr (FUSE) {
#pragma unroll
        for (int mt = 0; mt < MT; ++mt)
#pragma unroll
            for (int r = 0; r < 4; ++r)
                atomicAdd(d1o + (size_t)(row0 + mt * 16 + quad * 4 + r) * 256 +
                              wv * (256 / W) + l16,
                          a1s[mt * 4 + r][tid]);
    }
}

// --- explicit wrappers: per-instantiation occupancy/register pinning -------
// lstm1: W=4, MT=1, 1024 blocks x 256thr (4 blocks/CU).
__global__ __launch_bounds__(256, 4)
void lstm1_kernel(const __half* __restrict__ xin, const __half* __restrict__ PB,
                  const float* __restrict__ bf, const float* __restrict__ bb,
                  __half* __restrict__ out)
{
    lstm_body<128, 64, false, 4, 1>(xin, PB, bf, bb, out, nullptr, nullptr);
}

// lstm2: W=8, MT=2, 512 blocks x 512thr (2 blocks/CU).
__global__ __launch_bounds__(512, 4)
void lstm2_kernel(const __half* __restrict__ xin, const __half* __restrict__ PB,
                  const float* __restrict__ bf, const float* __restrict__ bb,
                  __half* __restrict__ out)
{
    lstm_body<128, 128, false, 8, 2>(xin, PB, bf, bb, out, nullptr, nullptr);
}

// lstm3: W=16, MT=2, 512 blocks x 1024thr = 2 blocks/CU, 8 waves/SIMD
// (waves_per_eu(8,8) -> 64 regs/wave incl AGPR; acc=32 fits). LDS/block:
// hb 33.8KB + a1s 32KB = 65.8KB -> 131.6KB/CU for 2 blocks (<160KB).
__global__
__attribute__((amdgpu_flat_work_group_size(1024, 1024), amdgpu_waves_per_eu(8, 8)))
void lstm3_kernel(const __half* __restrict__ xin, const __half* __restrict__ PB,
                  const float* __restrict__ bf, const float* __restrict__ bb,
                  const __half* __restrict__ PD1, float* __restrict__ d1o)
{
    lstm_body<256, 256, true, 16, 2>(xin, PB, bf, bb, nullptr, PD1, d1o);
}

// ---------------------------------------------------------------------------
__global__ __launch_bounds__(256)
void zero_f4(float* __restrict__ p)
{
    const size_t i = ((size_t)blockIdx.x * 256 + threadIdx.x) * 4;
    *(float4*)(p + i) = float4{0.0f, 0.0f, 0.0f, 0.0f};
}

// ---------------------------------------------------------------------------
// Tail: relu(d1o+d1b) -> dense2(256->128) relu -> dense3(128->64) relu ->
// batchnorm -> logits(64->26) -> softmax. One block = 16 batch rows.
// ---------------------------------------------------------------------------
__global__ __launch_bounds__(256)
void tail_kernel(const float* __restrict__ a1g, const float* __restrict__ d1b,
                 const float* __restrict__ d2w, const float* __restrict__ d2b,
                 const float* __restrict__ d3w, const float* __restrict__ d3b,
                 const float* __restrict__ bng, const float* __restrict__ bnb,
                 const float* __restrict__ bnm, const float* __restrict__ bnv,
                 const float* __restrict__ ow,  const float* __restrict__ ob,
                 float* __restrict__ outp)
{
    const int tid = threadIdx.x;
    const int row0 = blockIdx.x * 16;

    __shared__ float A1[16][256];
    __shared__ float A2[16][128];
    __shared__ float A3[16][64];
    __shared__ float LG[16][26];

    for (int i = tid; i < 16 * 256; i += 256) {
        const int c = i & 255;
        A1[i >> 8][c] = fmaxf(a1g[(size_t)row0 * 256 + i] + d1b[c], 0.0f);
    }
    __syncthreads();

    { // dense2: 16x128 outputs, 8 per thread
        const int r = tid >> 4, j0 = (tid & 15) * 8;
        float acc[8];
#pragma unroll
        for (int q = 0; q < 8; ++q) acc[q] = d2b[j0 + q];
#pragma unroll 4
        for (int k = 0; k < 256; ++k) {
            const float av = A1[r][k];
            const float* wr = d2w + (size_t)k * 128 + j0;
            float w8[8];
            *(float4*)w8       = *(const float4*)wr;
            *(float4*)(w8 + 4) = *(const float4*)(wr + 4);
#pragma unroll
            for (int q = 0; q < 8; ++q) acc[q] = fmaf(av, w8[q], acc[q]);
        }
#pragma unroll
        for (int q = 0; q < 8; ++q) A2[r][j0 + q] = fmaxf(acc[q], 0.0f);
    }
    __syncthreads();

    { // dense3 + batchnorm
        const int r = tid >> 4, j0 = (tid & 15) * 4;
        float acc[4];
#pragma unroll
        for (int q = 0; q < 4; ++q) acc[q] = d3b[j0 + q];
#pragma unroll 4
        for (int k = 0; k < 128; ++k) {
            const float av = A2[r][k];
            float w4[4];
            *(float4*)w4 = *(const float4*)(d3w + (size_t)k * 64 + j0);
#pragma unroll
            for (int q = 0; q < 4; ++q) acc[q] = fmaf(av, w4[q], acc[q]);
        }
#pragma unroll
        for (int q = 0; q < 4; ++q) {
            const int jc = j0 + q;
            const float h = fmaxf(acc[q], 0.0f);
            const float sc = bng[jc] * rsqrtf(bnv[jc] + 0.001f);
            A3[r][jc] = (h - bnm[jc]) * sc + bnb[jc];
        }
    }
    __syncthreads();

    for (int i = tid; i < 16 * 26; i += 256) { // logits
        const int r = i / 26, jc = i % 26;
        float acc = ob[jc];
#pragma unroll 4
        for (int k = 0; k < 64; ++k) acc = fmaf(A3[r][k], ow[(size_t)k * 26 + jc], acc);
        LG[r][jc] = acc;
    }
    __syncthreads();

    if (tid < 16) { // softmax
        const int r = tid;
        float m = -1e30f;
        for (int c = 0; c < 26; ++c) m = fmaxf(m, LG[r][c]);
        float s = 0.0f;
        float e[26];
        for (int c = 0; c < 26; ++c) { e[c] = __expf(LG[r][c] - m); s += e[c]; }
        const float inv = 1.0f / s;
        for (int c = 0; c < 26; ++c)
            outp[(size_t)(row0 + r) * 26 + c] = e[c] * inv;
    }
}

// ---------------------------------------------------------------------------
extern "C" void kernel_launch(void* const* d_in, const int* in_sizes, int n_in,
                              void* d_out, int out_size, void* d_ws, size_t ws_size,
                              hipStream_t stream)
{
    const float* x   = (const float*)d_in[0];
    const float* w1f = (const float*)d_in[1];
    const float* u1f = (const float*)d_in[2];
    const float* b1f = (const float*)d_in[3];
    const float* w1b = (const float*)d_in[4];
    const float* u1b = (const float*)d_in[5];
    const float* b1b = (const float*)d_in[6];
    const float* w2f = (const float*)d_in[7];
    const float* u2f = (const float*)d_in[8];
    const float* b2f = (const float*)d_in[9];
    const float* w2b = (const float*)d_in[10];
    const float* u2b = (const float*)d_in[11];
    const float* b2b = (const float*)d_in[12];
    const float* w3f = (const float*)d_in[13];
    const float* u3f = (const float*)d_in[14];
    const float* b3f = (const float*)d_in[15];
    const float* w3b = (const float*)d_in[16];
    const float* u3b = (const float*)d_in[17];
    const float* b3b = (const float*)d_in[18];
    const float* d1w = (const float*)d_in[19];
    const float* d1b = (const float*)d_in[20];
    const float* d2w = (const float*)d_in[21];
    const float* d2b = (const float*)d_in[22];
    const float* d3w = (const float*)d_in[23];
    const float* d3b = (const float*)d_in[24];
    const float* bng = (const float*)d_in[25];
    const float* bnb = (const float*)d_in[26];
    const float* bnm = (const float*)d_in[27];
    const float* bnv = (const float*)d_in[28];
    const float* ow  = (const float*)d_in[29];
    const float* ob  = (const float*)d_in[30];

    // Workspace map (bytes). Proven safe footprint (R3): 189,333,504.
    //   h1  f16 (B,T,128) @ 0            .. 62,914,560
    //   h2  f16 (B,T,256) @ 62,914,560   .. 188,743,680
    //     x16 f16 (B,T,128) @ 62,914,560  (dead before lstm2 writes h2)
    //     PB1 @ 125,829,120 (196,608 B)   (dead before lstm2 writes h2)
    //   PB2 @ 188,743,680 (524,288 B)    .. 189,267,968
    //   after lstm2, h1 region reused:
    //     d1o fp32 @ 0 (8,388,608 B)
    //     PD1 @ 8,388,608 (7,864,320 B)
    //     PB3 @ 16,252,928 (2,097,152 B) .. 18,350,080
    char* wsb = (char*)d_ws;
    __half* h1  = (__half*)wsb;
    __half* h2  = (__half*)(wsb + 62914560);
    __half* x16 = (__half*)(wsb + 62914560);
    __half* PB1 = (__half*)(wsb + 125829120);
    __half* PB2 = (__half*)(wsb + 188743680);
    float*  d1o = (float*)wsb;
    __half* PD1 = (__half*)(wsb + 8388608);
    __half* PB3 = (__half*)(wsb + 16252928);

    const dim3 blk(256);

    x_to_f16<<<dim3(122880), blk, 0, stream>>>(x, x16);
    pack_b<126, 128,  64,  4><<<dim3( 384), blk, 0, stream>>>(w1f, u1f, w1b, u1b, PB1);
    pack_b<128, 128, 128,  8><<<dim3(1024), blk, 0, stream>>>(w2f, u2f, w2b, u2b, PB2);

    // lstm1: W=4, MT=1.
    lstm1_kernel<<<dim3(BATCH / 16, 2), dim3(256), 0, stream>>>(
        x16, PB1, b1f, b1b, h1);
    // lstm2: W=8, MT=2.
    lstm2_kernel<<<dim3(BATCH / 32, 2), dim3(512), 0, stream>>>(
        h1, PB2, b2f, b2b, h2);

    // h1 dead: carve d1o, PD1, PB3 out of its region
    zero_f4<<<dim3(2048), blk, 0, stream>>>(d1o);
    pack_b<256, 256, 256, 16><<<dim3(4096), blk, 0, stream>>>(w3f, u3f, w3b, u3b, PB3);
    pack_d1<16><<<dim3(15360), blk, 0, stream>>>(d1w, PD1);

    // lstm3: W=16, MT=2, 512 blocks (2/CU, 8 waves/SIMD).
    lstm3_kernel<<<dim3(BATCH / 32, 2), dim3(1024), 0, stream>>>(
        h2, PB3, b3f, b3b, PD1, d1o);

    tail_kernel<<<dim3(BATCH / 16), blk, 0, stream>>>(
        d1o, d1b, d2w, d2b, d3w, d3b, bng, bnb, bnm, bnv, ow, ob, (float*)d_out);
}

// Round 9
// 1706.639 us; speedup vs baseline: 1.0817x; 1.0817x over previous
//
#include <hip/hip_runtime.h>
#include <hip/hip_fp16.h>

#define TT 30
#define BATCH 8192

typedef _Float16 f16x8v __attribute__((ext_vector_type(8)));
typedef float    f32x4v __attribute__((ext_vector_type(4)));
typedef unsigned int u32x4v __attribute__((ext_vector_type(4)));

__device__ __forceinline__ float sigf(float x) { return 1.0f / (1.0f + __expf(-x)); }

__device__ __forceinline__ f16x8v ldb16(const __half* p) {
    return __builtin_bit_cast(f16x8v, *(const u32x4v*)p);
}
__device__ __forceinline__ f32x4v mfma16(f16x8v a, f16x8v b, f32x4v c) {
    return __builtin_amdgcn_mfma_f32_16x16x32_f16(a, b, c, 0, 0, 0);
}

// ---------------------------------------------------------------------------
// x (B,T,126) fp32 -> x16 (B,T,128) f16, zero-padded cols 126..127
// ---------------------------------------------------------------------------
__global__ __launch_bounds__(256)
void x_to_f16(const float* __restrict__ x, __half* __restrict__ x16)
{
    const size_t i = (size_t)blockIdx.x * 256 + threadIdx.x;  // < B*T*128
    const int k = (int)(i & 127);
    const size_t bt = i >> 7;
    x16[i] = (k < 126) ? __float2half(x[bt * 126 + k]) : __half(0.0f);
}

// ---------------------------------------------------------------------------
// Pack LSTM weights into MFMA B-fragment order, W waves per direction.
// Dest flat: [dir][wave W][nt NT][kt KT][lane 64][jj 8], fragment element
// B[k = kt*32 + (lane>>4)*8 + jj][col = g*U + w*(U/W) + jhi*16 + (lane&15)]
// with g = nt/JH, jhi = nt%JH, JH = U/(16W), NT = 4*JH.
// K rows: [W rows 0..DINP) (>=DINS zero-padded), then Urec rows.
// (Layout depends only on W, not on the M-tiling of the LSTM kernel.)
// ---------------------------------------------------------------------------
template<int DINS, int DINP, int U, int W>
__global__ __launch_bounds__(256)
void pack_b(const float* __restrict__ wf, const float* __restrict__ uf,
            const float* __restrict__ wb, const float* __restrict__ ub,
            __half* __restrict__ dst)
{
    constexpr int JH = U / (16 * W), NT = 4 * JH, KT = (DINP + U) / 32;
    const int i = blockIdx.x * 256 + threadIdx.x;   // < 2*W*NT*KT*512
    const int jj   = i & 7;
    const int lane = (i >> 3) & 63;
    int rest = i >> 9;
    const int kt = rest % KT; rest /= KT;
    const int nt = rest % NT; rest /= NT;
    const int w  = rest % W;
    const int d  = rest / W;
    const int g = nt / JH, jhi = nt % JH;
    const int col = g * U + w * (U / W) + jhi * 16 + (lane & 15);
    const int k = kt * 32 + (lane >> 4) * 8 + jj;
    const float* __restrict__ Wm = d ? wb : wf;
    const float* __restrict__ Ur = d ? ub : uf;
    float v;
    if (k < DINS)      v = Wm[(size_t)k * (4 * U) + col];
    else if (k < DINP) v = 0.0f;
    else               v = Ur[(size_t)(k - DINP) * (4 * U) + col];
    dst[i] = __float2half(v);
}

// ---------------------------------------------------------------------------
// Pack d1w (15360,256) into per-(t,dir) B-fragment slabs, W waves:
// [t 30][d 2][w W][nt NT1][kt 8][lane 64][jj 8], NT1 = 256/(16W);
// element = d1w[(t*512 + d*256 + k)*256 + n], k = kt*32+(lane>>4)*8+jj,
// n = w*(256/W) + nt*16 + (lane&15).
// ---------------------------------------------------------------------------
template<int W>
__global__ __launch_bounds__(256)
void pack_d1(const float* __restrict__ src, __half* __restrict__ dst)
{
    constexpr int NT1 = 256 / (16 * W);
    const int i = blockIdx.x * 256 + threadIdx.x;   // < 3,932,160
    const int jj   = i & 7;
    const int lane = (i >> 3) & 63;
    const int kt   = (i >> 9) & 7;
    int rest = i >> 12;
    const int nt = rest % NT1; rest /= NT1;
    const int w  = rest % W;   rest /= W;
    const int d  = rest & 1;
    const int t  = rest >> 1;
    const int n = w * (256 / W) + nt * 16 + (lane & 15);
    const int k = kt * 32 + (lane >> 4) * 8 + jj;
    dst[i] = __float2half(src[(size_t)(t * 512 + d * 256 + k) * 256 + n]);
}

// ---------------------------------------------------------------------------
// MFMA bidirectional LSTM layer body. Block = (MT*16) batch rows x one
// direction, W waves (64*W threads), iterates all TT steps.
// Per step: Z[M][4U] = [x_t | h] @ [W;U] + b via 16x16x32 f16 MFMA.
// Wave w owns N-columns {g*U + w*(U/W) + jhi*16 + c}.
// h (f16) double-buffered in LDS (row stride U+8) -> ONE barrier per step.
// c (fp32) in VGPRs at C-layout (row=quad*4+reg, col=lane&15).
// FUSE (lstm3): per-step rank-256 dense1 MFMA update; accumulator in LDS
// (a1s[MT*4][NTH], per-thread-private column), register-resident only
// during the dense1 phase (R7: killed the R2-R6 scratch spill).
// R8 diagnosis: doubling occupancy (47->96%) changed nothing; VALUBusy
// ~26-30% at ~10 VALU/MFMA = the SIMD issue port is eaten by per-lane
// 64-bit ADDRESS math (wv=tid>>6 not provably wave-uniform -> no SGPR-base
// loads; size_t offsets -> 64-bit adds). Fix here: wvu = readfirstlane
// (marks weight/slab bases wave-uniform -> global_load v,voff,s[base]) and
// all hot-loop offsets in unsigned 32-bit.
// ---------------------------------------------------------------------------
template<int DIN, int U, bool FUSE, int W, int MT>
__device__ __forceinline__
void lstm_body(const __half* __restrict__ xin,    // (B,T,DIN) f16
               const __half* __restrict__ PB,     // packed weights
               const float* __restrict__ biasf, const float* __restrict__ biasb,
               __half* __restrict__ out,          // (B,T,2U) f16 (non-FUSE)
               const __half* __restrict__ PD1, float* __restrict__ d1o)
{
    constexpr int NTH = 64 * W;
    constexpr int M = 16 * MT;
    constexpr int JH = U / (16 * W);          // per-gate 16-col tiles per wave
    constexpr int NT = 4 * JH;
    constexpr int KT = (DIN + U) / 32, KTI = DIN / 32;
    constexpr int HS = U + 8;
    constexpr int NT1 = FUSE ? (256 / (16 * W)) : 1;
    static_assert(!FUSE || NT1 == 1, "FUSE path assumes one 16-col dense1 tile per wave");
    const int dir = blockIdx.y;
    const int tid = threadIdx.x;
    const int lane = tid & 63;
    // wave index as a PROVABLY wave-uniform value (SGPR) -> all bases derived
    // from it become scalar; loads use SGPR-base + 32-bit voffset.
    const int wvu = __builtin_amdgcn_readfirstlane(tid >> 6);
    const int l16 = lane & 15, quad = lane >> 4;
    const int row0 = blockIdx.x * M;
    const float* __restrict__ bias = dir ? biasb : biasf;

    __shared__ __align__(16) __half hb[2][M][HS];
    // dense1 accumulator: per-thread-private column -> no conflicts, no races
    __shared__ float a1s[FUSE ? MT * 4 : 1][FUSE ? NTH : 1];

    float bg[NT];
#pragma unroll
    for (int nt = 0; nt < NT; ++nt) {
        const int g = nt / JH, jhi = nt % JH;
        bg[nt] = bias[g * U + wvu * (U / W) + jhi * 16 + l16];
    }

    float creg[MT][JH][4];
#pragma unroll
    for (int mt = 0; mt < MT; ++mt)
#pragma unroll
        for (int jhi = 0; jhi < JH; ++jhi)
#pragma unroll
            for (int r = 0; r < 4; ++r) creg[mt][jhi][r] = 0.0f;

    if constexpr (FUSE) {
#pragma unroll
        for (int j = 0; j < MT * 4; ++j) a1s[j][tid] = 0.0f;
    }

    for (int i = tid; i < M * HS; i += NTH) ((__half*)hb[0])[i] = __half(0.0f);
    __syncthreads();

    // 32-bit half-element offsets (all tensors < 2^32 halves):
    //   weights base: uniform (dir,wvu) part + per-lane lane*8
    //   x base: per-lane row part; mt/t/kt deltas are compile-time/loop consts
    const unsigned pbw = (unsigned)(dir * W + wvu) * (unsigned)(NT * KT * 512)
                       + (unsigned)lane * 8u;
    const unsigned xl = (unsigned)(row0 + l16) * (unsigned)(TT * DIN)
                      + (unsigned)quad * 8u;

    int pb = 0;
#pragma unroll 1
    for (int s = 0; s < TT; ++s) {
        const int t = dir ? (TT - 1 - s) : s;
        const unsigned xt = xl + (unsigned)t * (unsigned)DIN;

        f32x4v acc[MT][NT];
#pragma unroll
        for (int mt = 0; mt < MT; ++mt)
#pragma unroll
            for (int nt = 0; nt < NT; ++nt)
                acc[mt][nt] = f32x4v{bg[nt], bg[nt], bg[nt], bg[nt]};

        // ---- input contribution (K-tiles 0..KTI) ----
#pragma unroll 2
        for (int kt = 0; kt < KTI; ++kt) {
            f16x8v a[MT];
#pragma unroll
            for (int mt = 0; mt < MT; ++mt)
                a[mt] = ldb16(xin + (xt + (unsigned)(mt * 16 * TT * DIN)
                                        + (unsigned)kt * 32u));
            const unsigned bk = pbw + (unsigned)kt * 512u;
#pragma unroll
            for (int nt = 0; nt < NT; ++nt) {
                const f16x8v b = ldb16(PB + (bk + (unsigned)(nt * KT * 512)));
#pragma unroll
                for (int mt = 0; mt < MT; ++mt)
                    acc[mt][nt] = mfma16(a[mt], b, acc[mt][nt]);
            }
        }
        // ---- recurrent contribution (K-tiles KTI..KT) ----
#pragma unroll 2
        for (int kt = KTI; kt < KT; ++kt) {
            f16x8v a[MT];
#pragma unroll
            for (int mt = 0; mt < MT; ++mt)
                a[mt] = ldb16(&hb[pb][mt * 16 + l16][(kt - KTI) * 32 + quad * 8]);
            const unsigned bk = pbw + (unsigned)kt * 512u;
#pragma unroll
            for (int nt = 0; nt < NT; ++nt) {
                const f16x8v b = ldb16(PB + (bk + (unsigned)(nt * KT * 512)));
#pragma unroll
                for (int mt = 0; mt < MT; ++mt)
                    acc[mt][nt] = mfma16(a[mt], b, acc[mt][nt]);
            }
        }

        // ---- gates / state (C-layout: row=quad*4+r, col=l16) ----
        // h streamed straight to LDS (no staging array).
#pragma unroll
        for (int mt = 0; mt < MT; ++mt)
#pragma unroll
            for (int jhi = 0; jhi < JH; ++jhi)
#pragma unroll
                for (int r = 0; r < 4; ++r) {
                    const float zi = acc[mt][0 * JH + jhi][r];
                    const float zf = acc[mt][1 * JH + jhi][r];
                    const float zg = acc[mt][2 * JH + jhi][r];
                    const float zo = acc[mt][3 * JH + jhi][r];
                    const float cn = sigf(zf) * creg[mt][jhi][r] + sigf(zi) * fmaxf(zg, 0.0f);
                    creg[mt][jhi][r] = cn;
                    hb[1 - pb][mt * 16 + quad * 4 + r][wvu * (U / W) + jhi * 16 + l16] =
                        __float2half(sigf(zo) * fmaxf(cn, 0.0f));
                }
        __syncthreads();   // h(s) visible; also fences hb[pb] overwrite next step

        if constexpr (FUSE) {
            // dense1 rank-256 update: a1s += h_t @ d1w_slab(t,dir).
            // acc regs live only within this phase (load LDS -> mfma -> store).
            const unsigned sl = (unsigned)((t * 2 + dir) * W + wvu)
                              * (unsigned)(NT1 * 8 * 512) + (unsigned)lane * 8u;
            f32x4v c1[MT];
#pragma unroll
            for (int mt = 0; mt < MT; ++mt)
#pragma unroll
                for (int r = 0; r < 4; ++r) c1[mt][r] = a1s[mt * 4 + r][tid];
#pragma unroll 2
            for (int kt = 0; kt < 8; ++kt) {
                const f16x8v b = ldb16(PD1 + (sl + (unsigned)kt * 512u));
#pragma unroll
                for (int mt = 0; mt < MT; ++mt) {
                    const f16x8v a = ldb16(&hb[1 - pb][mt * 16 + l16][kt * 32 + quad * 8]);
                    c1[mt] = mfma16(a, b, c1[mt]);
                }
            }
#pragma unroll
            for (int mt = 0; mt < MT; ++mt)
#pragma unroll
                for (int r = 0; r < 4; ++r) a1s[mt * 4 + r][tid] = c1[mt][r];
        } else {
            // coalesced h-out: (B,T,2U), this block's M rows, dir half
            constexpr int CH = U / 8;   // 16B chunks per row
            for (int i = tid; i < M * CH; i += NTH) {
                const int r = i / CH, cc = (i % CH) * 8;
                const unsigned oo = ((unsigned)(row0 + r) * TT + (unsigned)t)
                                  * (unsigned)(2 * U) + (unsigned)(dir * U + cc);
                *(u32x4v*)(out + oo) = *(const u32x4v*)&hb[1 - pb][r][cc];
            }
        }
        pb ^= 1;
    }

    if constexpr (FUSE) {
#pragma unroll
        for (int mt = 0; mt < MT; ++mt)
#pragma unroll
            for (int r = 0; r < 4; ++r)
                atomicAdd(d1o + (size_t)(row0 + mt * 16 + quad * 4 + r) * 256 +
                              wvu * (256 / W) + l16,
                          a1s[mt * 4 + r][tid]);
    }
}

// --- explicit wrappers: per-instantiation occupancy/register pinning -------
// lstm1: W=4, MT=1, 1024 blocks x 256thr (4 blocks/CU).
__global__ __launch_bounds__(256, 4)
void lstm1_kernel(const __half* __restrict__ xin, const __half* __restrict__ PB,
                  const float* __restrict__ bf, const float* __restrict__ bb,
                  __half* __restrict__ out)
{
    lstm_body<128, 64, false, 4, 1>(xin, PB, bf, bb, out, nullptr, nullptr);
}

// lstm2: W=8, MT=2, 512 blocks x 512thr (2 blocks/CU).
__global__ __launch_bounds__(512, 4)
void lstm2_kernel(const __half* __restrict__ xin, const __half* __restrict__ PB,
                  const float* __restrict__ bf, const float* __restrict__ bb,
                  __half* __restrict__ out)
{
    lstm_body<128, 128, false, 8, 2>(xin, PB, bf, bb, out, nullptr, nullptr);
}

// lstm3: W=16, MT=4, 256 blocks x 1024thr (1/CU, best-measured R7 config),
// waves_per_eu(4,4) -> 128 regs/wave unified VGPR+AGPR. LDS 130 KB.
__global__
__attribute__((amdgpu_flat_work_group_size(1024, 1024), amdgpu_waves_per_eu(4, 4)))
void lstm3_kernel(const __half* __restrict__ xin, const __half* __restrict__ PB,
                  const float* __restrict__ bf, const float* __restrict__ bb,
                  const __half* __restrict__ PD1, float* __restrict__ d1o)
{
    lstm_body<256, 256, true, 16, 4>(xin, PB, bf, bb, nullptr, PD1, d1o);
}

// ---------------------------------------------------------------------------
__global__ __launch_bounds__(256)
void zero_f4(float* __restrict__ p)
{
    const size_t i = ((size_t)blockIdx.x * 256 + threadIdx.x) * 4;
    *(float4*)(p + i) = float4{0.0f, 0.0f, 0.0f, 0.0f};
}

// ---------------------------------------------------------------------------
// Tail: relu(d1o+d1b) -> dense2(256->128) relu -> dense3(128->64) relu ->
// batchnorm -> logits(64->26) -> softmax. One block = 16 batch rows.
// ---------------------------------------------------------------------------
__global__ __launch_bounds__(256)
void tail_kernel(const float* __restrict__ a1g, const float* __restrict__ d1b,
                 const float* __restrict__ d2w, const float* __restrict__ d2b,
                 const float* __restrict__ d3w, const float* __restrict__ d3b,
                 const float* __restrict__ bng, const float* __restrict__ bnb,
                 const float* __restrict__ bnm, const float* __restrict__ bnv,
                 const float* __restrict__ ow,  const float* __restrict__ ob,
                 float* __restrict__ outp)
{
    const int tid = threadIdx.x;
    const int row0 = blockIdx.x * 16;

    __shared__ float A1[16][256];
    __shared__ float A2[16][128];
    __shared__ float A3[16][64];
    __shared__ float LG[16][26];

    for (int i = tid; i < 16 * 256; i += 256) {
        const int c = i & 255;
        A1[i >> 8][c] = fmaxf(a1g[(size_t)row0 * 256 + i] + d1b[c], 0.0f);
    }
    __syncthreads();

    { // dense2: 16x128 outputs, 8 per thread
        const int r = tid >> 4, j0 = (tid & 15) * 8;
        float acc[8];
#pragma unroll
        for (int q = 0; q < 8; ++q) acc[q] = d2b[j0 + q];
#pragma unroll 4
        for (int k = 0; k < 256; ++k) {
            const float av = A1[r][k];
            const float* wr = d2w + (size_t)k * 128 + j0;
            float w8[8];
            *(float4*)w8       = *(const float4*)wr;
            *(float4*)(w8 + 4) = *(const float4*)(wr + 4);
#pragma unroll
            for (int q = 0; q < 8; ++q) acc[q] = fmaf(av, w8[q], acc[q]);
        }
#pragma unroll
        for (int q = 0; q < 8; ++q) A2[r][j0 + q] = fmaxf(acc[q], 0.0f);
    }
    __syncthreads();

    { // dense3 + batchnorm
        const int r = tid >> 4, j0 = (tid & 15) * 4;
        float acc[4];
#pragma unroll
        for (int q = 0; q < 4; ++q) acc[q] = d3b[j0 + q];
#pragma unroll 4
        for (int k = 0; k < 128; ++k) {
            const float av = A2[r][k];
            float w4[4];
            *(float4*)w4 = *(const float4*)(d3w + (size_t)k * 64 + j0);
#pragma unroll
            for (int q = 0; q < 4; ++q) acc[q] = fmaf(av, w4[q], acc[q]);
        }
#pragma unroll
        for (int q = 0; q < 4; ++q) {
            const int jc = j0 + q;
            const float h = fmaxf(acc[q], 0.0f);
            const float sc = bng[jc] * rsqrtf(bnv[jc] + 0.001f);
            A3[r][jc] = (h - bnm[jc]) * sc + bnb[jc];
        }
    }
    __syncthreads();

    for (int i = tid; i < 16 * 26; i += 256) { // logits
        const int r = i / 26, jc = i % 26;
        float acc = ob[jc];
#pragma unroll 4
        for (int k = 0; k < 64; ++k) acc = fmaf(A3[r][k], ow[(size_t)k * 26 + jc], acc);
        LG[r][jc] = acc;
    }
    __syncthreads();

    if (tid < 16) { // softmax
        const int r = tid;
        float m = -1e30f;
        for (int c = 0; c < 26; ++c) m = fmaxf(m, LG[r][c]);
        float s = 0.0f;
        float e[26];
        for (int c = 0; c < 26; ++c) { e[c] = __expf(LG[r][c] - m); s += e[c]; }
        const float inv = 1.0f / s;
        for (int c = 0; c < 26; ++c)
            outp[(size_t)(row0 + r) * 26 + c] = e[c] * inv;
    }
}

// ---------------------------------------------------------------------------
extern "C" void kernel_launch(void* const* d_in, const int* in_sizes, int n_in,
                              void* d_out, int out_size, void* d_ws, size_t ws_size,
                              hipStream_t stream)
{
    const float* x   = (const float*)d_in[0];
    const float* w1f = (const float*)d_in[1];
    const float* u1f = (const float*)d_in[2];
    const float* b1f = (const float*)d_in[3];
    const float* w1b = (const float*)d_in[4];
    const float* u1b = (const float*)d_in[5];
    const float* b1b = (const float*)d_in[6];
    const float* w2f = (const float*)d_in[7];
    const float* u2f = (const float*)d_in[8];
    const float* b2f = (const float*)d_in[9];
    const float* w2b = (const float*)d_in[10];
    const float* u2b = (const float*)d_in[11];
    const float* b2b = (const float*)d_in[12];
    const float* w3f = (const float*)d_in[13];
    const float* u3f = (const float*)d_in[14];
    const float* b3f = (const float*)d_in[15];
    const float* w3b = (const float*)d_in[16];
    const float* u3b = (const float*)d_in[17];
    const float* b3b = (const float*)d_in[18];
    const float* d1w = (const float*)d_in[19];
    const float* d1b = (const float*)d_in[20];
    const float* d2w = (const float*)d_in[21];
    const float* d2b = (const float*)d_in[22];
    const float* d3w = (const float*)d_in[23];
    const float* d3b = (const float*)d_in[24];
    const float* bng = (const float*)d_in[25];
    const float* bnb = (const float*)d_in[26];
    const float* bnm = (const float*)d_in[27];
    const float* bnv = (const float*)d_in[28];
    const float* ow  = (const float*)d_in[29];
    const float* ob  = (const float*)d_in[30];

    // Workspace map (bytes). Proven safe footprint (R3): 189,333,504.
    //   h1  f16 (B,T,128) @ 0            .. 62,914,560
    //   h2  f16 (B,T,256) @ 62,914,560   .. 188,743,680
    //     x16 f16 (B,T,128) @ 62,914,560  (dead before lstm2 writes h2)
    //     PB1 @ 125,829,120 (196,608 B)   (dead before lstm2 writes h2)
    //   PB2 @ 188,743,680 (524,288 B)    .. 189,267,968
    //   after lstm2, h1 region reused:
    //     d1o fp32 @ 0 (8,388,608 B)
    //     PD1 @ 8,388,608 (7,864,320 B)
    //     PB3 @ 16,252,928 (2,097,152 B) .. 18,350,080
    char* wsb = (char*)d_ws;
    __half* h1  = (__half*)wsb;
    __half* h2  = (__half*)(wsb + 62914560);
    __half* x16 = (__half*)(wsb + 62914560);
    __half* PB1 = (__half*)(wsb + 125829120);
    __half* PB2 = (__half*)(wsb + 188743680);
    float*  d1o = (float*)wsb;
    __half* PD1 = (__half*)(wsb + 8388608);
    __half* PB3 = (__half*)(wsb + 16252928);

    const dim3 blk(256);

    x_to_f16<<<dim3(122880), blk, 0, stream>>>(x, x16);
    pack_b<126, 128,  64,  4><<<dim3( 384), blk, 0, stream>>>(w1f, u1f, w1b, u1b, PB1);
    pack_b<128, 128, 128,  8><<<dim3(1024), blk, 0, stream>>>(w2f, u2f, w2b, u2b, PB2);

    // lstm1: W=4, MT=1.
    lstm1_kernel<<<dim3(BATCH / 16, 2), dim3(256), 0, stream>>>(
        x16, PB1, b1f, b1b, h1);
    // lstm2: W=8, MT=2.
    lstm2_kernel<<<dim3(BATCH / 32, 2), dim3(512), 0, stream>>>(
        h1, PB2, b2f, b2b, h2);

    // h1 dead: carve d1o, PD1, PB3 out of its region
    zero_f4<<<dim3(2048), blk, 0, stream>>>(d1o);
    pack_b<256, 256, 256, 16><<<dim3(4096), blk, 0, stream>>>(w3f, u3f, w3b, u3b, PB3);
    pack_d1<16><<<dim3(15360), blk, 0, stream>>>(d1w, PD1);

    // lstm3: W=16, MT=4, 256 blocks (1/CU), SGPR-base addressing.
    lstm3_kernel<<<dim3(BATCH / 64, 2), dim3(1024), 0, stream>>>(
        h2, PB3, b3f, b3b, PD1, d1o);

    tail_kernel<<<dim3(BATCH / 16), blk, 0, stream>>>(
        d1o, d1b, d2w, d2b, d3w, d3b, bng, bnb, bnm, bnv, ow, ob, (float*)d_out);
}

// Round 10
// 1695.426 us; speedup vs baseline: 1.0888x; 1.0066x over previous
//
#include <hip/hip_runtime.h>
#include <hip/hip_fp16.h>

#define TT 30
#define BATCH 8192

typedef _Float16 f16x8v __attribute__((ext_vector_type(8)));
typedef float    f32x4v __attribute__((ext_vector_type(4)));
typedef unsigned int u32x4v __attribute__((ext_vector_type(4)));

__device__ __forceinline__ float sigf(float x) { return 1.0f / (1.0f + __expf(-x)); }

__device__ __forceinline__ f16x8v ldb16(const __half* p) {
    return __builtin_bit_cast(f16x8v, *(const u32x4v*)p);
}
__device__ __forceinline__ f32x4v mfma16(f16x8v a, f16x8v b, f32x4v c) {
    return __builtin_amdgcn_mfma_f32_16x16x32_f16(a, b, c, 0, 0, 0);
}

// ---------------------------------------------------------------------------
// x (B,T,126) fp32 -> x16 (B,T,128) f16, zero-padded cols 126..127
// ---------------------------------------------------------------------------
__global__ __launch_bounds__(256)
void x_to_f16(const float* __restrict__ x, __half* __restrict__ x16)
{
    const size_t i = (size_t)blockIdx.x * 256 + threadIdx.x;  // < B*T*128
    const int k = (int)(i & 127);
    const size_t bt = i >> 7;
    x16[i] = (k < 126) ? __float2half(x[bt * 126 + k]) : __half(0.0f);
}

// ---------------------------------------------------------------------------
// Pack LSTM weights into MFMA B-fragment order, W waves per direction.
// Dest flat: [dir][wave W][nt NT][kt KT][lane 64][jj 8], fragment element
// B[k = kt*32 + (lane>>4)*8 + jj][col = g*U + w*(U/W) + jhi*16 + (lane&15)]
// with g = nt/JH, jhi = nt%JH, JH = U/(16W), NT = 4*JH.
// K rows: [W rows 0..DINP) (>=DINS zero-padded), then Urec rows.
// (Layout depends only on W, not on the M-tiling of the LSTM kernel.)
// ---------------------------------------------------------------------------
template<int DINS, int DINP, int U, int W>
__global__ __launch_bounds__(256)
void pack_b(const float* __restrict__ wf, const float* __restrict__ uf,
            const float* __restrict__ wb, const float* __restrict__ ub,
            __half* __restrict__ dst)
{
    constexpr int JH = U / (16 * W), NT = 4 * JH, KT = (DINP + U) / 32;
    const int i = blockIdx.x * 256 + threadIdx.x;   // < 2*W*NT*KT*512
    const int jj   = i & 7;
    const int lane = (i >> 3) & 63;
    int rest = i >> 9;
    const int kt = rest % KT; rest /= KT;
    const int nt = rest % NT; rest /= NT;
    const int w  = rest % W;
    const int d  = rest / W;
    const int g = nt / JH, jhi = nt % JH;
    const int col = g * U + w * (U / W) + jhi * 16 + (lane & 15);
    const int k = kt * 32 + (lane >> 4) * 8 + jj;
    const float* __restrict__ Wm = d ? wb : wf;
    const float* __restrict__ Ur = d ? ub : uf;
    float v;
    if (k < DINS)      v = Wm[(size_t)k * (4 * U) + col];
    else if (k < DINP) v = 0.0f;
    else               v = Ur[(size_t)(k - DINP) * (4 * U) + col];
    dst[i] = __float2half(v);
}

// ---------------------------------------------------------------------------
// Pack d1w (15360,256) into per-(t,dir) B-fragment slabs, W waves:
// [t 30][d 2][w W][nt NT1][kt 8][lane 64][jj 8], NT1 = 256/(16W);
// element = d1w[(t*512 + d*256 + k)*256 + n], k = kt*32+(lane>>4)*8+jj,
// n = w*(256/W) + nt*16 + (lane&15).
// ---------------------------------------------------------------------------
template<int W>
__global__ __launch_bounds__(256)
void pack_d1(const float* __restrict__ src, __half* __restrict__ dst)
{
    constexpr int NT1 = 256 / (16 * W);
    const int i = blockIdx.x * 256 + threadIdx.x;   // < 3,932,160
    const int jj   = i & 7;
    const int lane = (i >> 3) & 63;
    const int kt   = (i >> 9) & 7;
    int rest = i >> 12;
    const int nt = rest % NT1; rest /= NT1;
    const int w  = rest % W;   rest /= W;
    const int d  = rest & 1;
    const int t  = rest >> 1;
    const int n = w * (256 / W) + nt * 16 + (lane & 15);
    const int k = kt * 32 + (lane >> 4) * 8 + jj;
    dst[i] = __float2half(src[(size_t)(t * 512 + d * 256 + k) * 256 + n]);
}

// ---------------------------------------------------------------------------
// MFMA bidirectional LSTM layer body. Block = (MT*16) batch rows x one
// direction, W waves (64*W threads), iterates all TT steps.
// Per step: Z[M][4U] = [x_t | h] @ [W;U] + b via 16x16x32 f16 MFMA.
// Wave w owns N-columns {g*U + w*(U/W) + jhi*16 + c}.
// h (f16) double-buffered in LDS (row stride U+8) -> ONE barrier per step.
// c (fp32) in VGPRs at C-layout (row=quad*4+reg, col=lane&15).
// FUSE (lstm3): per-step rank-256 dense1 MFMA update; accumulator in LDS
// (a1s[MT*4][NTH], per-thread-private column), register-resident only
// during the dense1 phase (R7: killed the R2-R6 scratch spill).
// R9 diagnosis: ~70% of step cycles are exposed-latency stall (MfmaUtil 23%
// invariant to occupancy R8, addressing R9; VALUBusy includes the MFMA pipe
// so non-MFMA VALU is only ~6%). Cause: `unroll 1` s-loop back-edge splits
// the schedulable region -- dense1(s) compute and input(s+1)/recurrent(s+1)
// loads sit in different basic blocks, so each phase eats its own L2
// latency serially. Fix here: ROTATED LOOP. Iteration s runs
//   gates(s) -> barrier -> [ dense1(s) | input(s+1) | recurrent(s+1) ]
// -- one basic block of 24 kt-groups of loads + all MFMAs, letting the
// scheduler hoist weight loads under compute. One barrier/step preserved:
// gates writes hb[hw]; all post-barrier readers use hb[hw]; next gates
// writes hb[hw^1] whose prior readers are fenced by the previous barrier.
// Accumulation order per output is unchanged (init, input kts, recurrent
// kts) -> bit-identical numerics.
// ---------------------------------------------------------------------------
template<int DIN, int U, bool FUSE, int W, int MT>
__device__ __forceinline__
void lstm_body(const __half* __restrict__ xin,    // (B,T,DIN) f16
               const __half* __restrict__ PB,     // packed weights
               const float* __restrict__ biasf, const float* __restrict__ biasb,
               __half* __restrict__ out,          // (B,T,2U) f16 (non-FUSE)
               const __half* __restrict__ PD1, float* __restrict__ d1o)
{
    constexpr int NTH = 64 * W;
    constexpr int M = 16 * MT;
    constexpr int JH = U / (16 * W);          // per-gate 16-col tiles per wave
    constexpr int NT = 4 * JH;
    constexpr int KT = (DIN + U) / 32, KTI = DIN / 32;
    constexpr int HS = U + 8;
    constexpr int NT1 = FUSE ? (256 / (16 * W)) : 1;
    static_assert(!FUSE || NT1 == 1, "FUSE path assumes one 16-col dense1 tile per wave");
    const int dir = blockIdx.y;
    const int tid = threadIdx.x;
    const int lane = tid & 63;
    // wave index as a PROVABLY wave-uniform value (SGPR base loads).
    const int wvu = __builtin_amdgcn_readfirstlane(tid >> 6);
    const int l16 = lane & 15, quad = lane >> 4;
    const int row0 = blockIdx.x * M;
    const float* __restrict__ bias = dir ? biasb : biasf;

    __shared__ __align__(16) __half hb[2][M][HS];
    // dense1 accumulator: per-thread-private column -> no conflicts, no races
    __shared__ float a1s[FUSE ? MT * 4 : 1][FUSE ? NTH : 1];

    float bg[NT];
#pragma unroll
    for (int nt = 0; nt < NT; ++nt) {
        const int g = nt / JH, jhi = nt % JH;
        bg[nt] = bias[g * U + wvu * (U / W) + jhi * 16 + l16];
    }

    float creg[MT][JH][4];
#pragma unroll
    for (int mt = 0; mt < MT; ++mt)
#pragma unroll
        for (int jhi = 0; jhi < JH; ++jhi)
#pragma unroll
            for (int r = 0; r < 4; ++r) creg[mt][jhi][r] = 0.0f;

    if constexpr (FUSE) {
#pragma unroll
        for (int j = 0; j < MT * 4; ++j) a1s[j][tid] = 0.0f;
    }

    for (int i = tid; i < M * HS; i += NTH) ((__half*)hb[0])[i] = __half(0.0f);
    __syncthreads();

    // 32-bit half-element offsets (all tensors < 2^32 halves).
    const unsigned pbw = (unsigned)(dir * W + wvu) * (unsigned)(NT * KT * 512)
                       + (unsigned)lane * 8u;
    const unsigned xl = (unsigned)(row0 + l16) * (unsigned)(TT * DIN)
                      + (unsigned)quad * 8u;

    f32x4v acc[MT][NT];

    auto zinit = [&]() {
#pragma unroll
        for (int mt = 0; mt < MT; ++mt)
#pragma unroll
            for (int nt = 0; nt < NT; ++nt)
                acc[mt][nt] = f32x4v{bg[nt], bg[nt], bg[nt], bg[nt]};
    };

    auto input_phase = [&](int t_) {
        const unsigned xt = xl + (unsigned)t_ * (unsigned)DIN;
#pragma unroll 2
        for (int kt = 0; kt < KTI; ++kt) {
            f16x8v a[MT];
#pragma unroll
            for (int mt = 0; mt < MT; ++mt)
                a[mt] = ldb16(xin + (xt + (unsigned)(mt * 16 * TT * DIN)
                                        + (unsigned)kt * 32u));
            const unsigned bk = pbw + (unsigned)kt * 512u;
#pragma unroll
            for (int nt = 0; nt < NT; ++nt) {
                const f16x8v b = ldb16(PB + (bk + (unsigned)(nt * KT * 512)));
#pragma unroll
                for (int mt = 0; mt < MT; ++mt)
                    acc[mt][nt] = mfma16(a[mt], b, acc[mt][nt]);
            }
        }
    };

    auto recur_phase = [&](int hr) {
#pragma unroll 2
        for (int kt = KTI; kt < KT; ++kt) {
            f16x8v a[MT];
#pragma unroll
            for (int mt = 0; mt < MT; ++mt)
                a[mt] = ldb16(&hb[hr][mt * 16 + l16][(kt - KTI) * 32 + quad * 8]);
            const unsigned bk = pbw + (unsigned)kt * 512u;
#pragma unroll
            for (int nt = 0; nt < NT; ++nt) {
                const f16x8v b = ldb16(PB + (bk + (unsigned)(nt * KT * 512)));
#pragma unroll
                for (int mt = 0; mt < MT; ++mt)
                    acc[mt][nt] = mfma16(a[mt], b, acc[mt][nt]);
            }
        }
    };

    // gates: consume acc -> creg, stream h(s) straight into hb[hw_]
    auto gates = [&](int hw_) {
#pragma unroll
        for (int mt = 0; mt < MT; ++mt)
#pragma unroll
            for (int jhi = 0; jhi < JH; ++jhi)
#pragma unroll
                for (int r = 0; r < 4; ++r) {
                    const float zi = acc[mt][0 * JH + jhi][r];
                    const float zf = acc[mt][1 * JH + jhi][r];
                    const float zg = acc[mt][2 * JH + jhi][r];
                    const float zo = acc[mt][3 * JH + jhi][r];
                    const float cn = sigf(zf) * creg[mt][jhi][r] + sigf(zi) * fmaxf(zg, 0.0f);
                    creg[mt][jhi][r] = cn;
                    hb[hw_][mt * 16 + quad * 4 + r][wvu * (U / W) + jhi * 16 + l16] =
                        __float2half(sigf(zo) * fmaxf(cn, 0.0f));
                }
    };

    // tail: FUSE -> dense1 rank-256 update; else coalesced h-out at time t_
    auto tail_phase = [&](int t_, int hw_) {
        if constexpr (FUSE) {
            const unsigned sl = (unsigned)((t_ * 2 + dir) * W + wvu)
                              * (unsigned)(NT1 * 8 * 512) + (unsigned)lane * 8u;
            f32x4v c1[MT];
#pragma unroll
            for (int mt = 0; mt < MT; ++mt)
#pragma unroll
                for (int r = 0; r < 4; ++r) c1[mt][r] = a1s[mt * 4 + r][tid];
#pragma unroll 2
            for (int kt = 0; kt < 8; ++kt) {
                const f16x8v b = ldb16(PD1 + (sl + (unsigned)kt * 512u));
#pragma unroll
                for (int mt = 0; mt < MT; ++mt) {
                    const f16x8v a = ldb16(&hb[hw_][mt * 16 + l16][kt * 32 + quad * 8]);
                    c1[mt] = mfma16(a, b, c1[mt]);
                }
            }
#pragma unroll
            for (int mt = 0; mt < MT; ++mt)
#pragma unroll
                for (int r = 0; r < 4; ++r) a1s[mt * 4 + r][tid] = c1[mt][r];
        } else {
            constexpr int CH = U / 8;   // 16B chunks per row
            for (int i = tid; i < M * CH; i += NTH) {
                const int r = i / CH, cc = (i % CH) * 8;
                const unsigned oo = ((unsigned)(row0 + r) * TT + (unsigned)t_)
                                  * (unsigned)(2 * U) + (unsigned)(dir * U + cc);
                *(u32x4v*)(out + oo) = *(const u32x4v*)&hb[hw_][r][cc];
            }
        }
    };

    // ---- rotated pipeline ----
    // prologue: Z(0) = bias + X(t0)@W + h(-1)=0 @ U (hb[0] zeroed above)
    zinit();
    input_phase(dir ? TT - 1 : 0);
    recur_phase(0);

    int hw = 1;
#pragma unroll 1
    for (int s = 0; s < TT - 1; ++s) {
        gates(hw);                         // h(s) -> hb[hw]
        __syncthreads();                   // h(s) visible to all waves
        tail_phase(dir ? TT - 1 - s : s, hw);
        zinit();
        input_phase(dir ? TT - 2 - s : s + 1);
        recur_phase(hw);                   // reads h(s) = hb[hw]
        hw ^= 1;
    }
    gates(hw);
    __syncthreads();
    tail_phase(dir ? 0 : TT - 1, hw);

    if constexpr (FUSE) {
#pragma unroll
        for (int mt = 0; mt < MT; ++mt)
#pragma unroll
            for (int r = 0; r < 4; ++r)
                atomicAdd(d1o + (size_t)(row0 + mt * 16 + quad * 4 + r) * 256 +
                              wvu * (256 / W) + l16,
                          a1s[mt * 4 + r][tid]);
    }
}

// --- explicit wrappers: per-instantiation occupancy/register pinning -------
// lstm1: W=4, MT=1, 1024 blocks x 256thr (4 blocks/CU).
__global__ __launch_bounds__(256, 4)
void lstm1_kernel(const __half* __restrict__ xin, const __half* __restrict__ PB,
                  const float* __restrict__ bf, const float* __restrict__ bb,
                  __half* __restrict__ out)
{
    lstm_body<128, 64, false, 4, 1>(xin, PB, bf, bb, out, nullptr, nullptr);
}

// lstm2: W=8, MT=2, 512 blocks x 512thr (2 blocks/CU).
__global__ __launch_bounds__(512, 4)
void lstm2_kernel(const __half* __restrict__ xin, const __half* __restrict__ PB,
                  const float* __restrict__ bf, const float* __restrict__ bb,
                  __half* __restrict__ out)
{
    lstm_body<128, 128, false, 8, 2>(xin, PB, bf, bb, out, nullptr, nullptr);
}

// lstm3: W=16, MT=4, 256 blocks x 1024thr (1/CU), waves_per_eu(4,4) ->
// 128 regs/wave unified VGPR+AGPR. LDS 130 KB.
__global__
__attribute__((amdgpu_flat_work_group_size(1024, 1024), amdgpu_waves_per_eu(4, 4)))
void lstm3_kernel(const __half* __restrict__ xin, const __half* __restrict__ PB,
                  const float* __restrict__ bf, const float* __restrict__ bb,
                  const __half* __restrict__ PD1, float* __restrict__ d1o)
{
    lstm_body<256, 256, true, 16, 4>(xin, PB, bf, bb, nullptr, PD1, d1o);
}

// ---------------------------------------------------------------------------
__global__ __launch_bounds__(256)
void zero_f4(float* __restrict__ p)
{
    const size_t i = ((size_t)blockIdx.x * 256 + threadIdx.x) * 4;
    *(float4*)(p + i) = float4{0.0f, 0.0f, 0.0f, 0.0f};
}

// ---------------------------------------------------------------------------
// Tail: relu(d1o+d1b) -> dense2(256->128) relu -> dense3(128->64) relu ->
// batchnorm -> logits(64->26) -> softmax. One block = 16 batch rows.
// ---------------------------------------------------------------------------
__global__ __launch_bounds__(256)
void tail_kernel(const float* __restrict__ a1g, const float* __restrict__ d1b,
                 const float* __restrict__ d2w, const float* __restrict__ d2b,
                 const float* __restrict__ d3w, const float* __restrict__ d3b,
                 const float* __restrict__ bng, const float* __restrict__ bnb,
                 const float* __restrict__ bnm, const float* __restrict__ bnv,
                 const float* __restrict__ ow,  const float* __restrict__ ob,
                 float* __restrict__ outp)
{
    const int tid = threadIdx.x;
    const int row0 = blockIdx.x * 16;

    __shared__ float A1[16][256];
    __shared__ float A2[16][128];
    __shared__ float A3[16][64];
    __shared__ float LG[16][26];

    for (int i = tid; i < 16 * 256; i += 256) {
        const int c = i & 255;
        A1[i >> 8][c] = fmaxf(a1g[(size_t)row0 * 256 + i] + d1b[c], 0.0f);
    }
    __syncthreads();

    { // dense2: 16x128 outputs, 8 per thread
        const int r = tid >> 4, j0 = (tid & 15) * 8;
        float acc[8];
#pragma unroll
        for (int q = 0; q < 8; ++q) acc[q] = d2b[j0 + q];
#pragma unroll 4
        for (int k = 0; k < 256; ++k) {
            const float av = A1[r][k];
            const float* wr = d2w + (size_t)k * 128 + j0;
            float w8[8];
            *(float4*)w8       = *(const float4*)wr;
            *(float4*)(w8 + 4) = *(const float4*)(wr + 4);
#pragma unroll
            for (int q = 0; q < 8; ++q) acc[q] = fmaf(av, w8[q], acc[q]);
        }
#pragma unroll
        for (int q = 0; q < 8; ++q) A2[r][j0 + q] = fmaxf(acc[q], 0.0f);
    }
    __syncthreads();

    { // dense3 + batchnorm
        const int r = tid >> 4, j0 = (tid & 15) * 4;
        float acc[4];
#pragma unroll
        for (int q = 0; q < 4; ++q) acc[q] = d3b[j0 + q];
#pragma unroll 4
        for (int k = 0; k < 128; ++k) {
            const float av = A2[r][k];
            float w4[4];
            *(float4*)w4 = *(const float4*)(d3w + (size_t)k * 64 + j0);
#pragma unroll
            for (int q = 0; q < 4; ++q) acc[q] = fmaf(av, w4[q], acc[q]);
        }
#pragma unroll
        for (int q = 0; q < 4; ++q) {
            const int jc = j0 + q;
            const float h = fmaxf(acc[q], 0.0f);
            const float sc = bng[jc] * rsqrtf(bnv[jc] + 0.001f);
            A3[r][jc] = (h - bnm[jc]) * sc + bnb[jc];
        }
    }
    __syncthreads();

    for (int i = tid; i < 16 * 26; i += 256) { // logits
        const int r = i / 26, jc = i % 26;
        float acc = ob[jc];
#pragma unroll 4
        for (int k = 0; k < 64; ++k) acc = fmaf(A3[r][k], ow[(size_t)k * 26 + jc], acc);
        LG[r][jc] = acc;
    }
    __syncthreads();

    if (tid < 16) { // softmax
        const int r = tid;
        float m = -1e30f;
        for (int c = 0; c < 26; ++c) m = fmaxf(m, LG[r][c]);
        float s = 0.0f;
        float e[26];
        for (int c = 0; c < 26; ++c) { e[c] = __expf(LG[r][c] - m); s += e[c]; }
        const float inv = 1.0f / s;
        for (int c = 0; c < 26; ++c)
            outp[(size_t)(row0 + r) * 26 + c] = e[c] * inv;
    }
}

// ---------------------------------------------------------------------------
extern "C" void kernel_launch(void* const* d_in, const int* in_sizes, int n_in,
                              void* d_out, int out_size, void* d_ws, size_t ws_size,
                              hipStream_t stream)
{
    const float* x   = (const float*)d_in[0];
    const float* w1f = (const float*)d_in[1];
    const float* u1f = (const float*)d_in[2];
    const float* b1f = (const float*)d_in[3];
    const float* w1b = (const float*)d_in[4];
    const float* u1b = (const float*)d_in[5];
    const float* b1b = (const float*)d_in[6];
    const float* w2f = (const float*)d_in[7];
    const float* u2f = (const float*)d_in[8];
    const float* b2f = (const float*)d_in[9];
    const float* w2b = (const float*)d_in[10];
    const float* u2b = (const float*)d_in[11];
    const float* b2b = (const float*)d_in[12];
    const float* w3f = (const float*)d_in[13];
    const float* u3f = (const float*)d_in[14];
    const float* b3f = (const float*)d_in[15];
    const float* w3b = (const float*)d_in[16];
    const float* u3b = (const float*)d_in[17];
    const float* b3b = (const float*)d_in[18];
    const float* d1w = (const float*)d_in[19];
    const float* d1b = (const float*)d_in[20];
    const float* d2w = (const float*)d_in[21];
    const float* d2b = (const float*)d_in[22];
    const float* d3w = (const float*)d_in[23];
    const float* d3b = (const float*)d_in[24];
    const float* bng = (const float*)d_in[25];
    const float* bnb = (const float*)d_in[26];
    const float* bnm = (const float*)d_in[27];
    const float* bnv = (const float*)d_in[28];
    const float* ow  = (const float*)d_in[29];
    const float* ob  = (const float*)d_in[30];

    // Workspace map (bytes). Proven safe footprint (R3): 189,333,504.
    //   h1  f16 (B,T,128) @ 0            .. 62,914,560
    //   h2  f16 (B,T,256) @ 62,914,560   .. 188,743,680
    //     x16 f16 (B,T,128) @ 62,914,560  (dead before lstm2 writes h2)
    //     PB1 @ 125,829,120 (196,608 B)   (dead before lstm2 writes h2)
    //   PB2 @ 188,743,680 (524,288 B)    .. 189,267,968
    //   after lstm2, h1 region reused:
    //     d1o fp32 @ 0 (8,388,608 B)
    //     PD1 @ 8,388,608 (7,864,320 B)
    //     PB3 @ 16,252,928 (2,097,152 B) .. 18,350,080
    char* wsb = (char*)d_ws;
    __half* h1  = (__half*)wsb;
    __half* h2  = (__half*)(wsb + 62914560);
    __half* x16 = (__half*)(wsb + 62914560);
    __half* PB1 = (__half*)(wsb + 125829120);
    __half* PB2 = (__half*)(wsb + 188743680);
    float*  d1o = (float*)wsb;
    __half* PD1 = (__half*)(wsb + 8388608);
    __half* PB3 = (__half*)(wsb + 16252928);

    const dim3 blk(256);

    x_to_f16<<<dim3(122880), blk, 0, stream>>>(x, x16);
    pack_b<126, 128,  64,  4><<<dim3( 384), blk, 0, stream>>>(w1f, u1f, w1b, u1b, PB1);
    pack_b<128, 128, 128,  8><<<dim3(1024), blk, 0, stream>>>(w2f, u2f, w2b, u2b, PB2);

    // lstm1: W=4, MT=1.
    lstm1_kernel<<<dim3(BATCH / 16, 2), dim3(256), 0, stream>>>(
        x16, PB1, b1f, b1b, h1);
    // lstm2: W=8, MT=2.
    lstm2_kernel<<<dim3(BATCH / 32, 2), dim3(512), 0, stream>>>(
        h1, PB2, b2f, b2b, h2);

    // h1 dead: carve d1o, PD1, PB3 out of its region
    zero_f4<<<dim3(2048), blk, 0, stream>>>(d1o);
    pack_b<256, 256, 256, 16><<<dim3(4096), blk, 0, stream>>>(w3f, u3f, w3b, u3b, PB3);
    pack_d1<16><<<dim3(15360), blk, 0, stream>>>(d1w, PD1);

    // lstm3: W=16, MT=4, 256 blocks (1/CU), rotated-loop schedule.
    lstm3_kernel<<<dim3(BATCH / 64, 2), dim3(1024), 0, stream>>>(
        h2, PB3, b3f, b3b, PD1, d1o);

    tail_kernel<<<dim3(BATCH / 16), blk, 0, stream>>>(
        d1o, d1b, d2w, d2b, d3w, d3b, bng, bnb, bnm, bnv, ow, ob, (float*)d_out);
}